// Round 4
// baseline (31218.945 us; speedup 1.0000x reference)
//
#include <hip/hip_runtime.h>
#include <hip/hip_bf16.h>

#define HDIM 128

// ---- typed load/store helpers (storage type T, compute fp32) ----
__device__ __forceinline__ float ldf(const float* p, size_t i) { return p[i]; }
__device__ __forceinline__ float ldf(const __hip_bfloat16* p, size_t i) {
  return __bfloat162float(p[i]);
}
__device__ __forceinline__ void stf(float* p, size_t i, float v) { p[i] = v; }
__device__ __forceinline__ void stf(__hip_bfloat16* p, size_t i, float v) {
  p[i] = __float2bfloat16(v);
}

// ---- edge index read, layout-aware + clamped (fault-proof) ----
// f64: buffer is int64[2E]; else int32[2E]. Result clamped to [0, nmax).
__device__ __forceinline__ int edge_at(const void* p, long long i, int f64,
                                       int nmax) {
  long long v = f64 ? ((const long long*)p)[i]
                    : (long long)((const int*)p)[i];
  if (v < 0) v = 0;
  if (v >= nmax) v = nmax - 1;
  return (int)v;
}

// ---- detect layout: flag!=0  <=>  some odd int32 word nonzero  <=>  int32 ----
// (int64 values < 2^31 have zero high-halves at odd word positions)
__global__ void detect_kernel(const int* __restrict__ e, int* __restrict__ flag) {
  int i = blockIdx.x * blockDim.x + threadIdx.x;  // 0..4095
  if (e[2 * i + 1] != 0) atomicOr(flag, 1);
}

// ---- zero fill ----
__global__ void zero_kernel(float4* __restrict__ p, size_t n4) {
  size_t i = blockIdx.x * (size_t)blockDim.x + threadIdx.x;
  size_t stride = (size_t)gridDim.x * blockDim.x;
  float4 z = make_float4(0.f, 0.f, 0.f, 0.f);
  for (; i < n4; i += stride) p[i] = z;
}

// ---- degree count (grid-stride) ----
__global__ void degree_kernel(const void* __restrict__ edges,
                              const int* __restrict__ flagp, int E,
                              float* __restrict__ deg, int n_dst) {
  int f64 = (*flagp == 0);
  for (int e = blockIdx.x * blockDim.x + threadIdx.x; e < E;
       e += gridDim.x * blockDim.x) {
    int d = edge_at(edges, (long long)E + e, f64, n_dst);
    atomicAdd(&deg[d], 1.0f);
  }
}

// ---- input projection: out = relu(x @ W^T + b) ----
template <int IN, typename T>
__global__ __launch_bounds__(256) void proj_kernel(
    const float* __restrict__ x, const float* __restrict__ W,
    const float* __restrict__ b, T* __restrict__ out, int nrows) {
  __shared__ float sW[HDIM * IN];
  __shared__ float sb[HDIM];
  int tid = threadIdx.x;
  for (int i = tid; i < HDIM * IN; i += 256) sW[i] = W[i];
  if (tid < HDIM) sb[tid] = b[tid];
  __syncthreads();
  int r = blockIdx.x * 2 + (tid >> 7);
  int o = tid & (HDIM - 1);
  if (r >= nrows) return;
  const float* xr = x + (size_t)r * IN;
  float acc = sb[o];
#pragma unroll
  for (int k = 0; k < IN; ++k) acc += xr[k] * sW[o * IN + k];
  stf(out, (size_t)r * HDIM + o, fmaxf(acc, 0.0f));
}

// ---- edge scatter (dst range [lo,hi)): accum[dst-lo] += feat[src] ----
template <typename T>
__global__ __launch_bounds__(256) void scatter_kernel(
    const T* __restrict__ feat, const void* __restrict__ edges,
    const int* __restrict__ flagp, int E, int n_src, int n_dst,
    float* __restrict__ accum, int lo, int hi) {
  int f64 = (*flagp == 0);
  int eh = threadIdx.x >> 7;
  int f = threadIdx.x & (HDIM - 1);
  for (int e = blockIdx.x * 2 + eh; e < E; e += gridDim.x * 2) {
    int d = edge_at(edges, (long long)E + e, f64, n_dst);
    if (d < lo || d >= hi) continue;
    int s = edge_at(edges, e, f64, n_src);
    float v = ldf(feat, (size_t)s * HDIM + f);
    atomicAdd(&accum[(size_t)(d - lo) * HDIM + f], v);
  }
}

// ---- SAGE update rows [lo,hi): out = relu((accum/deg)@Wl^T + bl + self@Wr^T)
// 8 rows/block; out may alias self (rows staged in LDS first, block-local).
template <typename T>
__global__ __launch_bounds__(256) void sage_update_kernel(
    const float* __restrict__ accum, const float* __restrict__ deg,
    const T* __restrict__ self, const float* __restrict__ Wl,
    const float* __restrict__ bl, const float* __restrict__ Wr,
    T* __restrict__ out, int lo, int hi) {
  const int R = 8;
  __shared__ float s_mean[R][HDIM];
  __shared__ float s_self[R][HDIM];
  int tid = threadIdx.x;
  int base = lo + blockIdx.x * R;
  for (int i = tid; i < R * HDIM; i += 256) {
    int r = i >> 7, k = i & (HDIM - 1);
    int row = base + r;
    if (row < hi) {
      float d = deg[row];
      d = d < 1.f ? 1.f : d;
      s_mean[r][k] = accum[(size_t)(row - lo) * HDIM + k] / d;
      s_self[r][k] = ldf(self, (size_t)row * HDIM + k);
    }
  }
  __syncthreads();
  int r = tid >> 5;
  int q = tid & 31;
  int row = base + r;
  if (row >= hi) return;
  float acc0 = bl[q], acc1 = bl[q + 32], acc2 = bl[q + 64], acc3 = bl[q + 96];
  const float4* __restrict__ Wl4 = (const float4*)Wl;
  const float4* __restrict__ Wr4 = (const float4*)Wr;
  const float4* m4 = (const float4*)s_mean[r];
  const float4* s4 = (const float4*)s_self[r];
#pragma unroll 4
  for (int k4 = 0; k4 < 32; ++k4) {
    const float4 m = m4[k4];
    const float4 s = s4[k4];
    float4 wl, wr;
    wl = Wl4[(size_t)q * 32 + k4];
    wr = Wr4[(size_t)q * 32 + k4];
    acc0 += m.x * wl.x + m.y * wl.y + m.z * wl.z + m.w * wl.w +
            s.x * wr.x + s.y * wr.y + s.z * wr.z + s.w * wr.w;
    wl = Wl4[((size_t)q + 32) * 32 + k4];
    wr = Wr4[((size_t)q + 32) * 32 + k4];
    acc1 += m.x * wl.x + m.y * wl.y + m.z * wl.z + m.w * wl.w +
            s.x * wr.x + s.y * wr.y + s.z * wr.z + s.w * wr.w;
    wl = Wl4[((size_t)q + 64) * 32 + k4];
    wr = Wr4[((size_t)q + 64) * 32 + k4];
    acc2 += m.x * wl.x + m.y * wl.y + m.z * wl.z + m.w * wl.w +
            s.x * wr.x + s.y * wr.y + s.z * wr.z + s.w * wr.w;
    wl = Wl4[((size_t)q + 96) * 32 + k4];
    wr = Wr4[((size_t)q + 96) * 32 + k4];
    acc3 += m.x * wl.x + m.y * wl.y + m.z * wl.z + m.w * wl.w +
            s.x * wr.x + s.y * wr.y + s.z * wr.z + s.w * wr.w;
  }
  stf(out, (size_t)row * HDIM + q, fmaxf(acc0, 0.f));
  stf(out, (size_t)row * HDIM + q + 32, fmaxf(acc1, 0.f));
  stf(out, (size_t)row * HDIM + q + 64, fmaxf(acc2, 0.f));
  stf(out, (size_t)row * HDIM + q + 96, fmaxf(acc3, 0.f));
}

// ---- head: out = hc @ Wh^T + bh (OUT=2) ----
template <typename T>
__global__ __launch_bounds__(256) void head_kernel(
    const T* __restrict__ hc, const float* __restrict__ Wh,
    const float* __restrict__ bh, float* __restrict__ out, int nrows) {
  __shared__ float sW[2 * HDIM];
  int tid = threadIdx.x;
  if (tid < 2 * HDIM) sW[tid] = Wh[tid];
  __syncthreads();
  int r = blockIdx.x * 64 + (tid >> 2);
  int sub = tid & 3;
  if (r >= nrows) return;
  const T* row = hc + (size_t)r * HDIM;
  float a0 = 0.f, a1 = 0.f;
#pragma unroll
  for (int i = 0; i < 32; ++i) {
    int k = sub * 32 + i;
    float v = ldf(row, k);
    a0 += v * sW[k];
    a1 += v * sW[HDIM + k];
  }
  a0 += __shfl_xor(a0, 1);
  a0 += __shfl_xor(a0, 2);
  a1 += __shfl_xor(a1, 1);
  a1 += __shfl_xor(a1, 2);
  if (sub == 0) {
    out[(size_t)r * 2] = a0 + bh[0];
    out[(size_t)r * 2 + 1] = a1 + bh[1];
  }
}

// ---------------- host-side tiered launcher ----------------
static const int NC = 400000, NN = 200000;

template <typename Tc, typename Tn>
static void run_all(void* const* d_in, const int* in_sizes, float* out,
                    char* ws, size_t ws_size, hipStream_t stream) {
  const float* x_cell = (const float*)d_in[0];
  const float* x_net = (const float*)d_in[1];
  const void* e_drives = d_in[2];
  const void* e_fans = d_in[3];
  const float* Wc = (const float*)d_in[4];
  const float* bc = (const float*)d_in[5];
  const float* Wn = (const float*)d_in[6];
  const float* bn = (const float*)d_in[7];
  const float* Wl_dn = (const float*)d_in[8];
  const float* bl_dn = (const float*)d_in[9];
  const float* Wr_dn = (const float*)d_in[10];
  const float* Wl_nc = (const float*)d_in[11];
  const float* bl_nc = (const float*)d_in[12];
  const float* Wr_nc = (const float*)d_in[13];
  const float* Wh = (const float*)d_in[14];
  const float* bh = (const float*)d_in[15];

  const int Ed = in_sizes[2] / 2;
  const int Ef = in_sizes[3] / 2;

  // layout: [flag 64B][degC NC f32][degN NN f32][hc][hnA][hnB][accum...]
  int* flag = (int*)ws;
  float* degC = (float*)(ws + 64);
  float* degN = degC + NC;
  size_t degB = 64 + (size_t)(NC + NN) * 4;
  Tc* hc = (Tc*)(ws + degB);
  size_t hcB = (size_t)NC * HDIM * sizeof(Tc);
  Tn* hnA = (Tn*)(ws + degB + hcB);
  size_t hnB_ = (size_t)NN * HDIM * sizeof(Tn);
  Tn* hnB = (Tn*)(ws + degB + hcB + hnB_);
  size_t fixedB = degB + hcB + 2 * hnB_;
  float* accum = (float*)(ws + fixedB);

  long long remB = (long long)ws_size - (long long)fixedB;
  int cap = remB > 0 ? (int)(remB / (HDIM * 4)) : 0;
  if (cap < 256) cap = 256;
  if (cap > NC) cap = NC;
  int capN = cap < NN ? cap : NN;
  int capC = cap;

  // flag + degrees (ws is poisoned each call -> re-zero, re-detect, re-count)
  zero_kernel<<<256, 256, 0, stream>>>((float4*)ws, degB / 16);
  detect_kernel<<<16, 256, 0, stream>>>((const int*)e_drives, flag);
  degree_kernel<<<2048, 256, 0, stream>>>(e_drives, flag, Ed, degN, NN);
  degree_kernel<<<2048, 256, 0, stream>>>(e_fans, flag, Ef, degC, NC);

  // input projections
  proj_kernel<16, Tc><<<NC / 2, 256, 0, stream>>>(x_cell, Wc, bc, hc, NC);
  proj_kernel<8, Tn><<<NN / 2, 256, 0, stream>>>(x_net, Wn, bn, hnA, NN);

  Tn* hn_cur = hnA;
  Tn* hn_nxt = hnB;

  for (int l = 0; l < 3; ++l) {
    const float* Wl_n = Wl_dn + (size_t)l * HDIM * HDIM;
    const float* bl_n = bl_dn + (size_t)l * HDIM;
    const float* Wr_n = Wr_dn + (size_t)l * HDIM * HDIM;
    const float* Wl_c = Wl_nc + (size_t)l * HDIM * HDIM;
    const float* bl_c = bl_nc + (size_t)l * HDIM;
    const float* Wr_c = Wr_nc + (size_t)l * HDIM * HDIM;

    // NET side: hn_nxt = relu(sage(hc -> nets)); hn_cur preserved
    for (int lo = 0; lo < NN; lo += capN) {
      int hi = lo + capN < NN ? lo + capN : NN;
      zero_kernel<<<2048, 256, 0, stream>>>((float4*)accum,
                                            (size_t)(hi - lo) * HDIM / 4);
      scatter_kernel<Tc><<<4096, 256, 0, stream>>>(hc, e_drives, flag, Ed,
                                                   NC, NN, accum, lo, hi);
      sage_update_kernel<Tn><<<(hi - lo + 7) / 8, 256, 0, stream>>>(
          accum, degN, hn_cur, Wl_n, bl_n, Wr_n, hn_nxt, lo, hi);
    }
    // CELL side: hc = relu(sage(hn_cur -> cells)) in place
    for (int lo = 0; lo < NC; lo += capC) {
      int hi = lo + capC < NC ? lo + capC : NC;
      zero_kernel<<<2048, 256, 0, stream>>>((float4*)accum,
                                            (size_t)(hi - lo) * HDIM / 4);
      scatter_kernel<Tn><<<4096, 256, 0, stream>>>(hn_cur, e_fans, flag, Ef,
                                                   NN, NC, accum, lo, hi);
      sage_update_kernel<Tc><<<(hi - lo + 7) / 8, 256, 0, stream>>>(
          accum, degC, hc, Wl_c, bl_c, Wr_c, hc, lo, hi);
    }
    Tn* t = hn_cur; hn_cur = hn_nxt; hn_nxt = t;
  }

  head_kernel<Tc><<<(NC + 63) / 64, 256, 0, stream>>>(hc, Wh, bh, out, NC);
}

extern "C" void kernel_launch(void* const* d_in, const int* in_sizes, int n_in,
                              void* d_out, int out_size, void* d_ws,
                              size_t ws_size, hipStream_t stream) {
  float* out = (float*)d_out;
  char* ws = (char*)d_ws;

  const size_t MB = 1000000;
  size_t degB = 64 + (size_t)(NC + NN) * 4;  // ~2.4 MB
  size_t hcF = (size_t)NC * HDIM * 4, hnF = (size_t)NN * HDIM * 4;
  const size_t ACCMIN = 32 * MB;

  if (ws_size >= degB + hcF + 2 * hnF + ACCMIN) {
    run_all<float, float>(d_in, in_sizes, out, ws, ws_size, stream);
  } else if (ws_size >= degB + hcF / 2 + 2 * hnF + ACCMIN) {
    run_all<__hip_bfloat16, float>(d_in, in_sizes, out, ws, ws_size, stream);
  } else {
    run_all<__hip_bfloat16, __hip_bfloat16>(d_in, in_sizes, out, ws, ws_size,
                                            stream);
  }
}

// Round 10
// 7008.839 us; speedup vs baseline: 4.4542x; 4.4542x over previous
//
#include <hip/hip_runtime.h>
#include <hip/hip_bf16.h>

#define HDIM 128
typedef __hip_bfloat16 bf16;

// ---- typed load/store helpers (storage T, compute fp32) ----
__device__ __forceinline__ float ldf(const float* p, size_t i) { return p[i]; }
__device__ __forceinline__ float ldf(const bf16* p, size_t i) {
  return __bfloat162float(p[i]);
}
__device__ __forceinline__ void stf(float* p, size_t i, float v) { p[i] = v; }
__device__ __forceinline__ void stf(bf16* p, size_t i, float v) {
  p[i] = __float2bfloat16(v);
}
// 2-element vector load at even element index i
__device__ __forceinline__ float2 ld2(const float* p, size_t i) {
  return *(const float2*)(p + i);
}
__device__ __forceinline__ float2 ld2(const bf16* p, size_t i) {
  unsigned u = *(const unsigned*)(p + i);
  float lo = __uint_as_float((u & 0xffffu) << 16);
  float hi = __uint_as_float(u & 0xffff0000u);
  return make_float2(lo, hi);
}

// ---- edge index read, layout-aware + clamped ----
__device__ __forceinline__ int edge_at(const void* p, long long i, int f64,
                                       int nmax) {
  long long v = f64 ? ((const long long*)p)[i]
                    : (long long)((const int*)p)[i];
  if (v < 0) v = 0;
  if (v >= nmax) v = nmax - 1;
  return (int)v;
}

// ---- detect: flag!=0 <=> some odd int32 word nonzero <=> int32 layout ----
// (edge_index is [2][E]; int64 little-endian values <2^31 have zero odd words)
__global__ void detect_kernel(const int* __restrict__ e, int* __restrict__ flag) {
  int i = blockIdx.x * blockDim.x + threadIdx.x;  // 0..4095
  if (e[2 * i + 1] != 0) atomicOr(flag, 1);
}

__global__ void zero_i(int* __restrict__ p, int n) {
  for (int i = blockIdx.x * blockDim.x + threadIdx.x; i < n;
       i += gridDim.x * blockDim.x)
    p[i] = 0;
}

// ---- CSR build: count ----
__global__ void count_kernel(const void* __restrict__ edges,
                             const int* __restrict__ flagp, int E,
                             int* __restrict__ cnt, int n_dst) {
  int f64 = (*flagp == 0);
  for (int e = blockIdx.x * blockDim.x + threadIdx.x; e < E;
       e += gridDim.x * blockDim.x) {
    int d = edge_at(edges, (long long)E + e, f64, n_dst);
    atomicAdd(&cnt[d], 1);
  }
}

// ---- CSR build: block-level inclusive scan ----
__global__ void scan1_kernel(const int* __restrict__ cnt,
                             int* __restrict__ rowptr, int* __restrict__ sums,
                             int N) {
  __shared__ int sd[256];
  int t = threadIdx.x;
  int i = blockIdx.x * 256 + t;
  int v = (i < N) ? cnt[i] : 0;
  sd[t] = v;
  __syncthreads();
  for (int off = 1; off < 256; off <<= 1) {
    int x = (t >= off) ? sd[t - off] : 0;
    __syncthreads();
    sd[t] += x;
    __syncthreads();
  }
  if (i < N) rowptr[i + 1] = sd[t];
  if (t == 255) sums[blockIdx.x] = sd[255];
}

// ---- CSR build: single-block exclusive scan of block sums ----
__global__ void scan2_kernel(int* __restrict__ sums, int P) {
  __shared__ int sd[256];
  __shared__ int carry_s;
  int t = threadIdx.x;
  if (t == 0) carry_s = 0;
  __syncthreads();
  for (int base = 0; base < P; base += 256) {
    int i = base + t;
    int v = (i < P) ? sums[i] : 0;
    sd[t] = v;
    __syncthreads();
    for (int off = 1; off < 256; off <<= 1) {
      int x = (t >= off) ? sd[t - off] : 0;
      __syncthreads();
      sd[t] += x;
      __syncthreads();
    }
    int incl = sd[t];
    int total = sd[255];
    int carry = carry_s;
    if (i < P) sums[i] = carry + incl - v;  // exclusive
    __syncthreads();
    if (t == 0) carry_s = carry + total;
    __syncthreads();
  }
}

// ---- CSR build: add block offsets; emit final rowptr + cursor ----
__global__ void scan3_kernel(int* __restrict__ rowptr, int* __restrict__ cursor,
                             const int* __restrict__ sums, int N) {
  for (int i = blockIdx.x * blockDim.x + threadIdx.x; i < N;
       i += gridDim.x * blockDim.x) {
    int b = i >> 8;
    int c = cursor[i];  // still holds cnt[i]
    int incl = rowptr[i + 1] + sums[b];
    rowptr[i + 1] = incl;
    cursor[i] = incl - c;  // row start
    if (i == 0) rowptr[0] = 0;
  }
}

// ---- CSR build: fill src lists ----
__global__ void fill_kernel(const void* __restrict__ edges,
                            const int* __restrict__ flagp, int E,
                            int* __restrict__ cursor, int* __restrict__ srcList,
                            int n_src, int n_dst) {
  int f64 = (*flagp == 0);
  for (int e = blockIdx.x * blockDim.x + threadIdx.x; e < E;
       e += gridDim.x * blockDim.x) {
    int d = edge_at(edges, (long long)E + e, f64, n_dst);
    int s = edge_at(edges, e, f64, n_src);
    int pos = atomicAdd(&cursor[d], 1);
    if (pos >= 0 && pos < E) srcList[pos] = s;
  }
}

// ---- input projection: out = relu(x @ W^T + b) ----
template <int IN, typename T>
__global__ __launch_bounds__(256) void proj_kernel(
    const float* __restrict__ x, const float* __restrict__ W,
    const float* __restrict__ b, T* __restrict__ out, int nrows) {
  __shared__ float sW[HDIM * IN];
  __shared__ float sb[HDIM];
  int tid = threadIdx.x;
  for (int i = tid; i < HDIM * IN; i += 256) sW[i] = W[i];
  if (tid < HDIM) sb[tid] = b[tid];
  __syncthreads();
  int r = blockIdx.x * 2 + (tid >> 7);
  int o = tid & (HDIM - 1);
  if (r >= nrows) return;
  const float* xr = x + (size_t)r * IN;
  float acc = sb[o];
#pragma unroll
  for (int k = 0; k < IN; ++k) acc += xr[k] * sW[o * IN + k];
  stf(out, (size_t)r * HDIM + o, fmaxf(acc, 0.0f));
}

// ---- fused SAGE layer: per block, 16 dst rows ----
// gather mean via CSR into LDS -> dual GEMV (Wl on mean, Wr on self) with
// fp32 LDS-staged weights (two phases) -> relu -> store.
// out may alias self_feat (each block reads only its own rows of self).
template <typename TSrc, typename TSelf, typename TOut>
__global__ __launch_bounds__(256) void sage_fused_kernel(
    const TSrc* __restrict__ src_feat, const TSelf* __restrict__ self_feat,
    const int* __restrict__ rowptr, const int* __restrict__ srcList, int n_src,
    int E, const float* __restrict__ Wl, const float* __restrict__ bl,
    const float* __restrict__ Wr, TOut* __restrict__ out, int nrows) {
  const int ROWS = 16;
  __shared__ float acts[ROWS][2 * HDIM];  // [row][0:128)=mean, [128:256)=self
  __shared__ float sW[HDIM * HDIM];       // one W matrix, swizzled
  int tid = threadIdx.x;
  int base = blockIdx.x * ROWS;
  int wid = tid >> 6, lane = tid & 63;

  // ---- gather phase: one wave per row (4 rows per wave) ----
  for (int rr = wid; rr < ROWS; rr += 4) {
    int row = base + rr;
    float m0 = 0.f, m1 = 0.f, s0 = 0.f, s1 = 0.f;
    if (row < nrows) {
      int beg = rowptr[row], end = rowptr[row + 1];
      if (beg < 0) beg = 0;
      if (end > E) end = E;
      for (int e = beg; e < end; ++e) {
        int s = srcList[e];
        s = s < 0 ? 0 : (s >= n_src ? n_src - 1 : s);
        float2 v = ld2(src_feat, (size_t)s * HDIM + 2 * lane);
        m0 += v.x;
        m1 += v.y;
      }
      float inv = 1.f / fmaxf((float)(end - beg), 1.f);
      m0 *= inv;
      m1 *= inv;
      float2 sv = ld2(self_feat, (size_t)row * HDIM + 2 * lane);
      s0 = sv.x;
      s1 = sv.y;
    }
    ((float2*)acts[rr])[lane] = make_float2(m0, m1);
    ((float2*)(acts[rr] + HDIM))[lane] = make_float2(s0, s1);
  }

  // ---- GEMV phases ----
  float acc[2][4] = {{0.f, 0.f, 0.f, 0.f}, {0.f, 0.f, 0.f, 0.f}};
  int oq = tid & 31, tr = tid >> 5;  // outputs oq+32j, rows tr and tr+8

  for (int ph = 0; ph < 2; ++ph) {
    const float* Wg = ph ? Wr : Wl;
    __syncthreads();  // acts ready (ph0) / sW no longer needed (ph1)
    {  // stage W [o][k] -> LDS swizzled: float4 col index k4 ^ (o&31)
      int o = tid >> 1, kh = tid & 1;
      int swz = o & 31;
      const float4* Wg4 = (const float4*)(Wg + (size_t)o * HDIM);
      float4* sW4 = (float4*)sW + o * 32;
#pragma unroll
      for (int j = 0; j < 16; ++j) {
        int k4 = kh * 16 + j;
        sW4[k4 ^ swz] = Wg4[k4];
      }
    }
    __syncthreads();
    const int kbase = ph * (HDIM / 4);
#pragma unroll 4
    for (int k4 = 0; k4 < 32; ++k4) {
      float4 m0 = ((const float4*)acts[tr])[kbase + k4];
      float4 m1 = ((const float4*)acts[tr + 8])[kbase + k4];
#pragma unroll
      for (int j = 0; j < 4; ++j) {
        int o = oq + 32 * j;
        float4 w = ((const float4*)sW)[o * 32 + (k4 ^ (o & 31))];
        acc[0][j] += m0.x * w.x + m0.y * w.y + m0.z * w.z + m0.w * w.w;
        acc[1][j] += m1.x * w.x + m1.y * w.y + m1.z * w.z + m1.w * w.w;
      }
    }
  }

  // ---- epilogue ----
#pragma unroll
  for (int r2 = 0; r2 < 2; ++r2) {
    int row = base + tr + 8 * r2;
    if (row < nrows) {
#pragma unroll
      for (int j = 0; j < 4; ++j) {
        int o = oq + 32 * j;
        stf(out, (size_t)row * HDIM + o, fmaxf(acc[r2][j] + bl[o], 0.f));
      }
    }
  }
}

// ---- head: out = hc @ Wh^T + bh (OUT=2) ----
template <typename T>
__global__ __launch_bounds__(256) void head_kernel(
    const T* __restrict__ hc, const float* __restrict__ Wh,
    const float* __restrict__ bh, float* __restrict__ out, int nrows) {
  __shared__ float sW[2 * HDIM];
  int tid = threadIdx.x;
  if (tid < 2 * HDIM) sW[tid] = Wh[tid];
  __syncthreads();
  int r = blockIdx.x * 64 + (tid >> 2);
  int sub = tid & 3;
  if (r >= nrows) return;
  const T* row = hc + (size_t)r * HDIM;
  float a0 = 0.f, a1 = 0.f;
#pragma unroll
  for (int i = 0; i < 16; ++i) {
    int k = sub * 32 + 2 * i;
    float2 v = ld2(row, k);
    a0 += v.x * sW[k] + v.y * sW[k + 1];
    a1 += v.x * sW[HDIM + k] + v.y * sW[HDIM + k + 1];
  }
  a0 += __shfl_xor(a0, 1);
  a0 += __shfl_xor(a0, 2);
  a1 += __shfl_xor(a1, 1);
  a1 += __shfl_xor(a1, 2);
  if (sub == 0) {
    out[(size_t)r * 2] = a0 + bh[0];
    out[(size_t)r * 2 + 1] = a1 + bh[1];
  }
}

// ---------------- host side ----------------
static const int NC = 400000, NN = 200000;

template <typename Tn>
static void run_all(void* const* d_in, const int* in_sizes, float* out,
                    char* ws, size_t ws_size, hipStream_t stream) {
  const float* x_cell = (const float*)d_in[0];
  const float* x_net = (const float*)d_in[1];
  const void* e_drives = d_in[2];
  const void* e_fans = d_in[3];
  const float* Wc = (const float*)d_in[4];
  const float* bc = (const float*)d_in[5];
  const float* Wn = (const float*)d_in[6];
  const float* bn = (const float*)d_in[7];
  const float* Wl_dn = (const float*)d_in[8];
  const float* bl_dn = (const float*)d_in[9];
  const float* Wr_dn = (const float*)d_in[10];
  const float* Wl_nc = (const float*)d_in[11];
  const float* bl_nc = (const float*)d_in[12];
  const float* Wr_nc = (const float*)d_in[13];
  const float* Wh = (const float*)d_in[14];
  const float* bh = (const float*)d_in[15];

  const int Ed = in_sizes[2] / 2;
  const int Ef = in_sizes[3] / 2;

  char* p = ws;
  auto alloc = [&](size_t bytes) {
    char* r = p;
    p += (bytes + 255) & ~(size_t)255;
    return r;
  };
  int* flag = (int*)alloc(64);
  int* rowptrN = (int*)alloc((size_t)(NN + 1) * 4);
  int* rowptrC = (int*)alloc((size_t)(NC + 1) * 4);
  int* curN = (int*)alloc((size_t)NN * 4);  // cnt -> cursor
  int* curC = (int*)alloc((size_t)NC * 4);
  int* sums = (int*)alloc(4096 * 4);
  int* srcD = (int*)alloc((size_t)Ed * 4);  // cell ids, CSR by net
  int* srcF = (int*)alloc((size_t)Ef * 4);  // net ids, CSR by cell
  bf16* hc = (bf16*)alloc((size_t)NC * HDIM * sizeof(bf16));
  Tn* hnA = (Tn*)alloc((size_t)NN * HDIM * sizeof(Tn));
  Tn* hnB = (Tn*)alloc((size_t)NN * HDIM * sizeof(Tn));
  (void)ws_size;

  const int PN = (NN + 255) / 256, PC = (NC + 255) / 256;

  // ---- CSR build (once per call; reused by all 3 layers) ----
  zero_i<<<1, 64, 0, stream>>>(flag, 16);
  zero_i<<<512, 256, 0, stream>>>(curN, NN);
  zero_i<<<512, 256, 0, stream>>>(curC, NC);
  detect_kernel<<<16, 256, 0, stream>>>((const int*)e_drives, flag);
  count_kernel<<<2048, 256, 0, stream>>>(e_drives, flag, Ed, curN, NN);
  count_kernel<<<2048, 256, 0, stream>>>(e_fans, flag, Ef, curC, NC);
  scan1_kernel<<<PN, 256, 0, stream>>>(curN, rowptrN, sums, NN);
  scan2_kernel<<<1, 256, 0, stream>>>(sums, PN);
  scan3_kernel<<<512, 256, 0, stream>>>(rowptrN, curN, sums, NN);
  scan1_kernel<<<PC, 256, 0, stream>>>(curC, rowptrC, sums, NC);
  scan2_kernel<<<1, 256, 0, stream>>>(sums, PC);
  scan3_kernel<<<512, 256, 0, stream>>>(rowptrC, curC, sums, NC);
  fill_kernel<<<2048, 256, 0, stream>>>(e_drives, flag, Ed, curN, srcD, NC, NN);
  fill_kernel<<<2048, 256, 0, stream>>>(e_fans, flag, Ef, curC, srcF, NN, NC);

  // ---- input projections ----
  proj_kernel<16, bf16><<<NC / 2, 256, 0, stream>>>(x_cell, Wc, bc, hc, NC);
  proj_kernel<8, Tn><<<NN / 2, 256, 0, stream>>>(x_net, Wn, bn, hnA, NN);

  Tn* hn_cur = hnA;
  Tn* hn_nxt = hnB;

  for (int l = 0; l < 3; ++l) {
    const float* Wl_n = Wl_dn + (size_t)l * HDIM * HDIM;
    const float* bl_n = bl_dn + (size_t)l * HDIM;
    const float* Wr_n = Wr_dn + (size_t)l * HDIM * HDIM;
    const float* Wl_c = Wl_nc + (size_t)l * HDIM * HDIM;
    const float* bl_c = bl_nc + (size_t)l * HDIM;
    const float* Wr_c = Wr_nc + (size_t)l * HDIM * HDIM;

    // nets: hn_nxt = relu(sage(hc -> nets, self=hn_cur))
    sage_fused_kernel<bf16, Tn, Tn><<<(NN + 15) / 16, 256, 0, stream>>>(
        hc, hn_cur, rowptrN, srcD, NC, Ed, Wl_n, bl_n, Wr_n, hn_nxt, NN);
    // cells: hc = relu(sage(hn_cur -> cells, self=hc)) in place
    sage_fused_kernel<Tn, bf16, bf16><<<(NC + 15) / 16, 256, 0, stream>>>(
        hn_cur, hc, rowptrC, srcF, NN, Ef, Wl_c, bl_c, Wr_c, hc, NC);
    Tn* t = hn_cur;
    hn_cur = hn_nxt;
    hn_nxt = t;
  }

  head_kernel<bf16><<<(NC + 63) / 64, 256, 0, stream>>>(hc, Wh, bh, out, NC);
}

extern "C" void kernel_launch(void* const* d_in, const int* in_sizes, int n_in,
                              void* d_out, int out_size, void* d_ws,
                              size_t ws_size, hipStream_t stream) {
  float* out = (float*)d_out;
  char* ws = (char*)d_ws;
  // fixed cost (bytes): csr ~17MB + hc(bf16) 102.4MB; hn pair fp32 204.8MB
  // or bf16 102.4MB. Choose fp32 hn when it fits (matches round-4 accuracy).
  const size_t FP32_NEED = 330000000;  // 17 + 102.4 + 204.8 MB + slack
  if (ws_size >= FP32_NEED) {
    run_all<float>(d_in, in_sizes, out, ws, ws_size, stream);
  } else {
    run_all<bf16>(d_in, in_sizes, out, ws, ws_size, stream);
  }
}

// Round 14
// 2098.773 us; speedup vs baseline: 14.8749x; 3.3395x over previous
//
#include <hip/hip_runtime.h>
#include <hip/hip_bf16.h>

#define HDIM 128
typedef __hip_bfloat16 bf16;
typedef __attribute__((ext_vector_type(8))) short short8;
typedef __attribute__((ext_vector_type(4))) float f32x4;

// ---- bf16 helpers (fp32 compute, bf16 storage) ----
__device__ __forceinline__ void stf(bf16* p, size_t i, float v) {
  p[i] = __float2bfloat16(v);
}
__device__ __forceinline__ unsigned short f2bf(float f) {
  unsigned u = __float_as_uint(f);
  unsigned r = u + 0x7fff + ((u >> 16) & 1);  // RNE
  return (unsigned short)(r >> 16);
}
__device__ __forceinline__ unsigned pack_bf16(float lo, float hi) {
  return ((unsigned)f2bf(hi) << 16) | f2bf(lo);
}
// 2 bf16 at even index -> 2 floats
__device__ __forceinline__ float2 ld2(const bf16* p, size_t i) {
  unsigned u = *(const unsigned*)(p + i);
  return make_float2(__uint_as_float(u << 16),
                     __uint_as_float(u & 0xffff0000u));
}

// ---- edge index read, layout-aware + clamped ----
__device__ __forceinline__ int edge_at(const void* p, long long i, int f64,
                                       int nmax) {
  long long v = f64 ? ((const long long*)p)[i]
                    : (long long)((const int*)p)[i];
  if (v < 0) v = 0;
  if (v >= nmax) v = nmax - 1;
  return (int)v;
}

// ---- detect: flag!=0 <=> some odd int32 word nonzero <=> int32 layout ----
__global__ void detect_kernel(const int* __restrict__ e, int* __restrict__ flag) {
  int i = blockIdx.x * blockDim.x + threadIdx.x;  // 0..4095
  if (e[2 * i + 1] != 0) atomicOr(flag, 1);
}

__global__ void zero_i(int* __restrict__ p, int n) {
  for (int i = blockIdx.x * blockDim.x + threadIdx.x; i < n;
       i += gridDim.x * blockDim.x)
    p[i] = 0;
}

// ---- CSR build: count ----
__global__ void count_kernel(const void* __restrict__ edges,
                             const int* __restrict__ flagp, int E,
                             int* __restrict__ cnt, int n_dst) {
  int f64 = (*flagp == 0);
  for (int e = blockIdx.x * blockDim.x + threadIdx.x; e < E;
       e += gridDim.x * blockDim.x) {
    int d = edge_at(edges, (long long)E + e, f64, n_dst);
    atomicAdd(&cnt[d], 1);
  }
}

// ---- CSR build: block-level inclusive scan ----
__global__ void scan1_kernel(const int* __restrict__ cnt,
                             int* __restrict__ rowptr, int* __restrict__ sums,
                             int N) {
  __shared__ int sd[256];
  int t = threadIdx.x;
  int i = blockIdx.x * 256 + t;
  int v = (i < N) ? cnt[i] : 0;
  sd[t] = v;
  __syncthreads();
  for (int off = 1; off < 256; off <<= 1) {
    int x = (t >= off) ? sd[t - off] : 0;
    __syncthreads();
    sd[t] += x;
    __syncthreads();
  }
  if (i < N) rowptr[i + 1] = sd[t];
  if (t == 255) sums[blockIdx.x] = sd[255];
}

// ---- CSR build: single-block exclusive scan of block sums ----
__global__ void scan2_kernel(int* __restrict__ sums, int P) {
  __shared__ int sd[256];
  __shared__ int carry_s;
  int t = threadIdx.x;
  if (t == 0) carry_s = 0;
  __syncthreads();
  for (int base = 0; base < P; base += 256) {
    int i = base + t;
    int v = (i < P) ? sums[i] : 0;
    sd[t] = v;
    __syncthreads();
    for (int off = 1; off < 256; off <<= 1) {
      int x = (t >= off) ? sd[t - off] : 0;
      __syncthreads();
      sd[t] += x;
      __syncthreads();
    }
    int incl = sd[t];
    int total = sd[255];
    int carry = carry_s;
    if (i < P) sums[i] = carry + incl - v;  // exclusive
    __syncthreads();
    if (t == 0) carry_s = carry + total;
    __syncthreads();
  }
}

// ---- CSR build: add block offsets; emit final rowptr + cursor ----
__global__ void scan3_kernel(int* __restrict__ rowptr, int* __restrict__ cursor,
                             const int* __restrict__ sums, int N) {
  for (int i = blockIdx.x * blockDim.x + threadIdx.x; i < N;
       i += gridDim.x * blockDim.x) {
    int b = i >> 8;
    int c = cursor[i];  // still holds cnt[i]
    int incl = rowptr[i + 1] + sums[b];
    rowptr[i + 1] = incl;
    cursor[i] = incl - c;  // row start
    if (i == 0) rowptr[0] = 0;
  }
}

// ---- CSR build: fill src lists ----
__global__ void fill_kernel(const void* __restrict__ edges,
                            const int* __restrict__ flagp, int E,
                            int* __restrict__ cursor, int* __restrict__ srcList,
                            int n_src, int n_dst) {
  int f64 = (*flagp == 0);
  for (int e = blockIdx.x * blockDim.x + threadIdx.x; e < E;
       e += gridDim.x * blockDim.x) {
    int d = edge_at(edges, (long long)E + e, f64, n_dst);
    int s = edge_at(edges, e, f64, n_src);
    int pos = atomicAdd(&cursor[d], 1);
    if (pos >= 0 && pos < E) srcList[pos] = s;
  }
}

// ---- W pre-convert: fp32 [Wl;Wr] -> bf16 B-fragment layout ----
// frag[side][idx], idx = ((T*8 + s)*64 + lane)*8 + j
//   element = Bcat[k][n], k = s*32 + (lane>>4)*8 + j, n = T*16 + (lane&15)
//   Bcat[k][n] = k<128 ? Wl[n][k] : Wr[n][k-128]
__global__ __launch_bounds__(256) void wfrag_kernel(
    const float* __restrict__ Wl_dn, const float* __restrict__ Wr_dn,
    const float* __restrict__ Wl_nc, const float* __restrict__ Wr_nc,
    bf16* __restrict__ frag) {
  int side = blockIdx.x >> 5;        // 0..5
  int layer = side >> 1;
  int cell = side & 1;
  const float* Wl = (cell ? Wl_nc : Wl_dn) + (size_t)layer * HDIM * HDIM;
  const float* Wr = (cell ? Wr_nc : Wr_dn) + (size_t)layer * HDIM * HDIM;
  bf16* out = frag + (size_t)side * 32768;
  int base = (blockIdx.x & 31) * 1024 + threadIdx.x * 4;
#pragma unroll
  for (int q = 0; q < 4; ++q) {
    int idx = base + q;
    int j = idx & 7;
    int lane = (idx >> 3) & 63;
    int s = (idx >> 9) & 7;
    int T = idx >> 12;
    int k = s * 32 + (lane >> 4) * 8 + j;
    int n = T * 16 + (lane & 15);
    float v = (k < 128) ? Wl[n * HDIM + k] : Wr[n * HDIM + (k - 128)];
    out[idx] = __float2bfloat16(v);
  }
}

// ---- input projection: out = relu(x @ W^T + b), bf16 out ----
template <int IN>
__global__ __launch_bounds__(256) void proj_kernel(
    const float* __restrict__ x, const float* __restrict__ W,
    const float* __restrict__ b, bf16* __restrict__ out, int nrows) {
  __shared__ float sW[HDIM * IN];
  __shared__ float sb[HDIM];
  int tid = threadIdx.x;
  for (int i = tid; i < HDIM * IN; i += 256) sW[i] = W[i];
  if (tid < HDIM) sb[tid] = b[tid];
  __syncthreads();
  int r = blockIdx.x * 2 + (tid >> 7);
  int o = tid & (HDIM - 1);
  if (r >= nrows) return;
  const float* xr = x + (size_t)r * IN;
  float acc = sb[o];
#pragma unroll
  for (int k = 0; k < IN; ++k) acc += xr[k] * sW[o * IN + k];
  stf(out, (size_t)r * HDIM + o, fmaxf(acc, 0.0f));
}

// ---- fused SAGE layer (MFMA): 16 dst rows per block, 256 threads ----
// Gather mean+self (bf16 -> fp32 -> bf16) into LDS acts[16][264] (pad 8),
// then out(16x128) = acts(16x256) @ Bcat(256x128) via mfma_f32_16x16x32_bf16.
// Each of 4 waves owns N-columns [w*32, w*32+32). B-frags streamed from the
// precomputed global fragment buffer (coalesced 16B/lane, L2-hot).
// out may alias self_feat (block reads self only at its own rows, staged
// before any write; cell-side neighbor reads come from the other array).
__global__ __launch_bounds__(256, 4) void sage_mfma_kernel(
    const bf16* __restrict__ src_feat, const bf16* __restrict__ self_feat,
    const int* __restrict__ rowptr, const int* __restrict__ srcList,
    int n_src, int E, const bf16* __restrict__ wfrag,
    const float* __restrict__ bl, bf16* __restrict__ out, int nrows) {
  __shared__ bf16 acts[16][264];  // [row][0:128)=mean, [128:256)=self, +8 pad
  int tid = threadIdx.x;
  int lane = tid & 63, w = tid >> 6;
  int base = blockIdx.x * 16;

  // ---- gather: wave w handles rows w, w+4, w+8, w+12; lane = 2 cols ----
  for (int rr = w; rr < 16; rr += 4) {
    int row = base + rr;
    float m0 = 0.f, m1 = 0.f;
    unsigned sv = 0u;
    if (row < nrows) {
      int beg = rowptr[row], end = rowptr[row + 1];
      if (beg < 0) beg = 0;
      if (end > E) end = E;
      for (int e = beg; e < end; ++e) {
        int s = srcList[e];
        s = s < 0 ? 0 : (s >= n_src ? n_src - 1 : s);
        unsigned u = *(const unsigned*)(src_feat + (size_t)s * HDIM + 2 * lane);
        m0 += __uint_as_float(u << 16);
        m1 += __uint_as_float(u & 0xffff0000u);
      }
      float inv = 1.f / fmaxf((float)(end - beg), 1.f);
      m0 *= inv;
      m1 *= inv;
      sv = *(const unsigned*)(self_feat + (size_t)row * HDIM + 2 * lane);
    }
    char* rowp = (char*)&acts[rr][0];
    *(unsigned*)(rowp + lane * 4) = pack_bf16(m0, m1);        // mean cols
    *(unsigned*)(rowp + 256 + lane * 4) = sv;                 // self cols
  }
  __syncthreads();

  // ---- GEMM: A-frag row=lane&15, k=(lane>>4)*8+j (contiguous b128) ----
  f32x4 acc0 = {0.f, 0.f, 0.f, 0.f};
  f32x4 acc1 = {0.f, 0.f, 0.f, 0.f};
  const char* abase = (const char*)&acts[0][0] + (lane & 15) * 528 +
                      (lane >> 4) * 16;
  const short8* b0p =
      (const short8*)(wfrag) + ((size_t)(w * 2) * 8 * 64 + lane);
  const short8* b1p =
      (const short8*)(wfrag) + ((size_t)(w * 2 + 1) * 8 * 64 + lane);
#pragma unroll
  for (int s = 0; s < 8; ++s) {
    short8 a = *(const short8*)(abase + s * 64);
    short8 b0 = b0p[s * 64];
    short8 b1 = b1p[s * 64];
    acc0 = __builtin_amdgcn_mfma_f32_16x16x32_bf16(a, b0, acc0, 0, 0, 0);
    acc1 = __builtin_amdgcn_mfma_f32_16x16x32_bf16(a, b1, acc1, 0, 0, 0);
  }

  // ---- epilogue: D row=(lane>>4)*4+j, col=lane&15 ----
  int col = lane & 15;
  int n0 = w * 32 + col, n1 = n0 + 16;
  float bv0 = bl[n0], bv1 = bl[n1];
  int mrow = (lane >> 4) * 4;
#pragma unroll
  for (int j = 0; j < 4; ++j) {
    int row = base + mrow + j;
    if (row < nrows) {
      stf(out, (size_t)row * HDIM + n0, fmaxf(acc0[j] + bv0, 0.f));
      stf(out, (size_t)row * HDIM + n1, fmaxf(acc1[j] + bv1, 0.f));
    }
  }
}

// ---- head: out = hc @ Wh^T + bh (OUT=2) ----
__global__ __launch_bounds__(256) void head_kernel(
    const bf16* __restrict__ hc, const float* __restrict__ Wh,
    const float* __restrict__ bh, float* __restrict__ out, int nrows) {
  __shared__ float sW[2 * HDIM];
  int tid = threadIdx.x;
  if (tid < 2 * HDIM) sW[tid] = Wh[tid];
  __syncthreads();
  int r = blockIdx.x * 64 + (tid >> 2);
  int sub = tid & 3;
  if (r >= nrows) return;
  const bf16* row = hc + (size_t)r * HDIM;
  float a0 = 0.f, a1 = 0.f;
#pragma unroll
  for (int i = 0; i < 16; ++i) {
    int k = sub * 32 + 2 * i;
    float2 v = ld2(row, k);
    a0 += v.x * sW[k] + v.y * sW[k + 1];
    a1 += v.x * sW[HDIM + k] + v.y * sW[HDIM + k + 1];
  }
  a0 += __shfl_xor(a0, 1);
  a0 += __shfl_xor(a0, 2);
  a1 += __shfl_xor(a1, 1);
  a1 += __shfl_xor(a1, 2);
  if (sub == 0) {
    out[(size_t)r * 2] = a0 + bh[0];
    out[(size_t)r * 2 + 1] = a1 + bh[1];
  }
}

// ---------------- host side ----------------
static const int NC = 400000, NN = 200000;

extern "C" void kernel_launch(void* const* d_in, const int* in_sizes, int n_in,
                              void* d_out, int out_size, void* d_ws,
                              size_t ws_size, hipStream_t stream) {
  const float* x_cell = (const float*)d_in[0];
  const float* x_net = (const float*)d_in[1];
  const void* e_drives = d_in[2];
  const void* e_fans = d_in[3];
  const float* Wc = (const float*)d_in[4];
  const float* bc = (const float*)d_in[5];
  const float* Wn = (const float*)d_in[6];
  const float* bn = (const float*)d_in[7];
  const float* Wl_dn = (const float*)d_in[8];
  const float* bl_dn = (const float*)d_in[9];
  const float* Wr_dn = (const float*)d_in[10];
  const float* Wl_nc = (const float*)d_in[11];
  const float* bl_nc = (const float*)d_in[12];
  const float* Wr_nc = (const float*)d_in[13];
  const float* Wh = (const float*)d_in[14];
  const float* bh = (const float*)d_in[15];
  float* out = (float*)d_out;

  const int Ed = in_sizes[2] / 2;
  const int Ef = in_sizes[3] / 2;

  char* p = (char*)d_ws;
  auto alloc = [&](size_t bytes) {
    char* r = p;
    p += (bytes + 255) & ~(size_t)255;
    return r;
  };
  int* flag = (int*)alloc(64);
  int* rowptrN = (int*)alloc((size_t)(NN + 1) * 4);
  int* rowptrC = (int*)alloc((size_t)(NC + 1) * 4);
  int* curN = (int*)alloc((size_t)NN * 4);
  int* curC = (int*)alloc((size_t)NC * 4);
  int* sums = (int*)alloc(4096 * 4);
  int* srcD = (int*)alloc((size_t)Ed * 4);   // cell ids, CSR by net
  int* srcF = (int*)alloc((size_t)Ef * 4);   // net ids, CSR by cell
  bf16* wfrag = (bf16*)alloc((size_t)6 * 32768 * sizeof(bf16));
  bf16* hc = (bf16*)alloc((size_t)NC * HDIM * sizeof(bf16));
  bf16* hnA = (bf16*)alloc((size_t)NN * HDIM * sizeof(bf16));
  bf16* hnB = (bf16*)alloc((size_t)NN * HDIM * sizeof(bf16));
  (void)ws_size;

  const int PN = (NN + 255) / 256, PC = (NC + 255) / 256;

  // ---- CSR build (once per call; reused by all 3 layers) ----
  zero_i<<<1, 64, 0, stream>>>(flag, 16);
  zero_i<<<512, 256, 0, stream>>>(curN, NN);
  zero_i<<<512, 256, 0, stream>>>(curC, NC);
  detect_kernel<<<16, 256, 0, stream>>>((const int*)e_drives, flag);
  count_kernel<<<2048, 256, 0, stream>>>(e_drives, flag, Ed, curN, NN);
  count_kernel<<<2048, 256, 0, stream>>>(e_fans, flag, Ef, curC, NC);
  scan1_kernel<<<PN, 256, 0, stream>>>(curN, rowptrN, sums, NN);
  scan2_kernel<<<1, 256, 0, stream>>>(sums, PN);
  scan3_kernel<<<512, 256, 0, stream>>>(rowptrN, curN, sums, NN);
  scan1_kernel<<<PC, 256, 0, stream>>>(curC, rowptrC, sums, NC);
  scan2_kernel<<<1, 256, 0, stream>>>(sums, PC);
  scan3_kernel<<<512, 256, 0, stream>>>(rowptrC, curC, sums, NC);
  fill_kernel<<<2048, 256, 0, stream>>>(e_drives, flag, Ed, curN, srcD, NC, NN);
  fill_kernel<<<2048, 256, 0, stream>>>(e_fans, flag, Ef, curC, srcF, NN, NC);

  // ---- W fragment pre-convert + input projections ----
  wfrag_kernel<<<192, 256, 0, stream>>>(Wl_dn, Wr_dn, Wl_nc, Wr_nc, wfrag);
  proj_kernel<16><<<NC / 2, 256, 0, stream>>>(x_cell, Wc, bc, hc, NC);
  proj_kernel<8><<<NN / 2, 256, 0, stream>>>(x_net, Wn, bn, hnA, NN);

  bf16* hn_cur = hnA;
  bf16* hn_nxt = hnB;

  for (int l = 0; l < 3; ++l) {
    // nets: hn_nxt = relu(sage(hc -> nets, self=hn_cur))
    sage_mfma_kernel<<<(NN + 15) / 16, 256, 0, stream>>>(
        hc, hn_cur, rowptrN, srcD, NC, Ed, wfrag + (size_t)(l * 2) * 32768,
        bl_dn + (size_t)l * HDIM, hn_nxt, NN);
    // cells: hc = relu(sage(hn_cur -> cells, self=hc)) in place
    sage_mfma_kernel<<<(NC + 15) / 16, 256, 0, stream>>>(
        hn_cur, hc, rowptrC, srcF, NN, Ef, wfrag + (size_t)(l * 2 + 1) * 32768,
        bl_nc + (size_t)l * HDIM, hc, NC);
    bf16* t = hn_cur;
    hn_cur = hn_nxt;
    hn_nxt = t;
  }

  head_kernel<<<(NC + 63) / 64, 256, 0, stream>>>(hc, Wh, bh, out, NC);
}

// Round 15
// 1450.920 us; speedup vs baseline: 21.5167x; 1.4465x over previous
//
#include <hip/hip_runtime.h>
#include <hip/hip_bf16.h>

#define HDIM 128
typedef __hip_bfloat16 bf16;
typedef __attribute__((ext_vector_type(8))) short short8;
typedef __attribute__((ext_vector_type(4))) float f32x4;

// ---- bf16 helpers (fp32 compute, bf16 storage) ----
__device__ __forceinline__ void stf(bf16* p, size_t i, float v) {
  p[i] = __float2bfloat16(v);
}
__device__ __forceinline__ unsigned short f2bf(float f) {
  unsigned u = __float_as_uint(f);
  unsigned r = u + 0x7fff + ((u >> 16) & 1);  // RNE
  return (unsigned short)(r >> 16);
}
__device__ __forceinline__ unsigned pack_bf16(float lo, float hi) {
  return ((unsigned)f2bf(hi) << 16) | f2bf(lo);
}
// 2 bf16 at even index -> 2 floats
__device__ __forceinline__ float2 ld2(const bf16* p, size_t i) {
  unsigned u = *(const unsigned*)(p + i);
  return make_float2(__uint_as_float(u << 16),
                     __uint_as_float(u & 0xffff0000u));
}

// ---- edge index read, layout-aware + clamped ----
__device__ __forceinline__ int edge_at(const void* p, long long i, int f64,
                                       int nmax) {
  long long v = f64 ? ((const long long*)p)[i]
                    : (long long)((const int*)p)[i];
  if (v < 0) v = 0;
  if (v >= nmax) v = nmax - 1;
  return (int)v;
}

// ---- detect: flag!=0 <=> some odd int32 word nonzero <=> int32 layout ----
__global__ void detect_kernel(const int* __restrict__ e, int* __restrict__ flag) {
  int i = blockIdx.x * blockDim.x + threadIdx.x;  // 0..4095
  if (e[2 * i + 1] != 0) atomicOr(flag, 1);
}

__global__ void zero_i(int* __restrict__ p, int n) {
  for (int i = blockIdx.x * blockDim.x + threadIdx.x; i < n;
       i += gridDim.x * blockDim.x)
    p[i] = 0;
}

// ---- CSR build: count ----
__global__ void count_kernel(const void* __restrict__ edges,
                             const int* __restrict__ flagp, int E,
                             int* __restrict__ cnt, int n_dst) {
  int f64 = (*flagp == 0);
  for (int e = blockIdx.x * blockDim.x + threadIdx.x; e < E;
       e += gridDim.x * blockDim.x) {
    int d = edge_at(edges, (long long)E + e, f64, n_dst);
    atomicAdd(&cnt[d], 1);
  }
}

// ---- CSR build: block-level inclusive scan ----
__global__ void scan1_kernel(const int* __restrict__ cnt,
                             int* __restrict__ rowptr, int* __restrict__ sums,
                             int N) {
  __shared__ int sd[256];
  int t = threadIdx.x;
  int i = blockIdx.x * 256 + t;
  int v = (i < N) ? cnt[i] : 0;
  sd[t] = v;
  __syncthreads();
  for (int off = 1; off < 256; off <<= 1) {
    int x = (t >= off) ? sd[t - off] : 0;
    __syncthreads();
    sd[t] += x;
    __syncthreads();
  }
  if (i < N) rowptr[i + 1] = sd[t];
  if (t == 255) sums[blockIdx.x] = sd[255];
}

// ---- CSR build: single-block exclusive scan of block sums ----
__global__ void scan2_kernel(int* __restrict__ sums, int P) {
  __shared__ int sd[256];
  __shared__ int carry_s;
  int t = threadIdx.x;
  if (t == 0) carry_s = 0;
  __syncthreads();
  for (int base = 0; base < P; base += 256) {
    int i = base + t;
    int v = (i < P) ? sums[i] : 0;
    sd[t] = v;
    __syncthreads();
    for (int off = 1; off < 256; off <<= 1) {
      int x = (t >= off) ? sd[t - off] : 0;
      __syncthreads();
      sd[t] += x;
      __syncthreads();
    }
    int incl = sd[t];
    int total = sd[255];
    int carry = carry_s;
    if (i < P) sums[i] = carry + incl - v;  // exclusive
    __syncthreads();
    if (t == 0) carry_s = carry + total;
    __syncthreads();
  }
}

// ---- CSR build: add block offsets; emit final rowptr + cursor ----
__global__ void scan3_kernel(int* __restrict__ rowptr, int* __restrict__ cursor,
                             const int* __restrict__ sums, int N) {
  for (int i = blockIdx.x * blockDim.x + threadIdx.x; i < N;
       i += gridDim.x * blockDim.x) {
    int b = i >> 8;
    int c = cursor[i];  // still holds cnt[i]
    int incl = rowptr[i + 1] + sums[b];
    rowptr[i + 1] = incl;
    cursor[i] = incl - c;  // row start
    if (i == 0) rowptr[0] = 0;
  }
}

// ---- CSR build: fill src lists ----
__global__ void fill_kernel(const void* __restrict__ edges,
                            const int* __restrict__ flagp, int E,
                            int* __restrict__ cursor, int* __restrict__ srcList,
                            int n_src, int n_dst) {
  int f64 = (*flagp == 0);
  for (int e = blockIdx.x * blockDim.x + threadIdx.x; e < E;
       e += gridDim.x * blockDim.x) {
    int d = edge_at(edges, (long long)E + e, f64, n_dst);
    int s = edge_at(edges, e, f64, n_src);
    int pos = atomicAdd(&cursor[d], 1);
    if (pos >= 0 && pos < E) srcList[pos] = s;
  }
}

// ---- W pre-convert: fp32 [Wl;Wr] -> bf16 B-fragment layout ----
// frag[side][idx], idx = ((T*8 + s)*64 + lane)*8 + j
//   element = Bcat[k][n], k = s*32 + (lane>>4)*8 + j, n = T*16 + (lane&15)
//   Bcat[k][n] = k<128 ? Wl[n][k] : Wr[n][k-128]
__global__ __launch_bounds__(256) void wfrag_kernel(
    const float* __restrict__ Wl_dn, const float* __restrict__ Wr_dn,
    const float* __restrict__ Wl_nc, const float* __restrict__ Wr_nc,
    bf16* __restrict__ frag) {
  int side = blockIdx.x >> 5;        // 0..5
  int layer = side >> 1;
  int cell = side & 1;
  const float* Wl = (cell ? Wl_nc : Wl_dn) + (size_t)layer * HDIM * HDIM;
  const float* Wr = (cell ? Wr_nc : Wr_dn) + (size_t)layer * HDIM * HDIM;
  bf16* out = frag + (size_t)side * 32768;
  int base = (blockIdx.x & 31) * 1024 + threadIdx.x * 4;
#pragma unroll
  for (int q = 0; q < 4; ++q) {
    int idx = base + q;
    int j = idx & 7;
    int lane = (idx >> 3) & 63;
    int s = (idx >> 9) & 7;
    int T = idx >> 12;
    int k = s * 32 + (lane >> 4) * 8 + j;
    int n = T * 16 + (lane & 15);
    float v = (k < 128) ? Wl[n * HDIM + k] : Wr[n * HDIM + (k - 128)];
    out[idx] = __float2bfloat16(v);
  }
}

// ---- input projection: out = relu(x @ W^T + b), bf16 out ----
// 8 rows/block; W row per-thread in REGISTERS (no LDS -> no bank conflicts);
// x rows staged in LDS (broadcast reads).
template <int IN>
__global__ __launch_bounds__(256) void proj_kernel(
    const float* __restrict__ x, const float* __restrict__ W,
    const float* __restrict__ b, bf16* __restrict__ out, int nrows) {
  __shared__ float sx[8 * IN];
  __shared__ float sb[HDIM];
  int tid = threadIdx.x;
  int o = tid & 127, rh = tid >> 7;
  float wreg[IN];
  const float4* W4 = (const float4*)(W + (size_t)o * IN);
#pragma unroll
  for (int q = 0; q < IN / 4; ++q) {
    float4 v = W4[q];
    wreg[4 * q] = v.x;
    wreg[4 * q + 1] = v.y;
    wreg[4 * q + 2] = v.z;
    wreg[4 * q + 3] = v.w;
  }
  if (tid < HDIM) sb[tid] = b[tid];
  int base = blockIdx.x * 8;
  if (tid < 8 * IN) {
    int r = base + tid / IN;
    sx[tid] = (r < nrows) ? x[(size_t)base * IN + tid] : 0.f;
  }
  __syncthreads();
  float bv = sb[o];
#pragma unroll
  for (int j = 0; j < 4; ++j) {
    int rr = rh * 4 + j;
    int row = base + rr;
    if (row < nrows) {
      float acc = bv;
#pragma unroll
      for (int k = 0; k < IN; ++k) acc += sx[rr * IN + k] * wreg[k];
      stf(out, (size_t)row * HDIM + o, fmaxf(acc, 0.f));
    }
  }
}

// ---- fused SAGE layer (MFMA): 16 dst rows per block, 256 threads ----
// Gather: 4 edges/iteration — quarter-wave (16 lanes x 16B) covers a full
// 256B source row; cross-quarter sum via shfl_xor(16/32). Then
// out(16x128) = acts(16x256) @ Bcat(256x128) via mfma_f32_16x16x32_bf16.
// out may alias self_feat (self staged to LDS before any write).
__global__ __launch_bounds__(256, 4) void sage_mfma_kernel(
    const bf16* __restrict__ src_feat, const bf16* __restrict__ self_feat,
    const int* __restrict__ rowptr, const int* __restrict__ srcList,
    int n_src, int E, const bf16* __restrict__ wfrag,
    const float* __restrict__ bl, bf16* __restrict__ out, int nrows) {
  __shared__ bf16 acts[16][264];  // [row][0:128)=mean, [128:256)=self, +8 pad
  int tid = threadIdx.x;
  int lane = tid & 63, w = tid >> 6;
  int sub = lane >> 4, ql = lane & 15;  // quarter id, lane-in-quarter
  int base = blockIdx.x * 16;

  // ---- gather: wave w handles rows w, w+4, w+8, w+12 ----
  for (int rr = w; rr < 16; rr += 4) {
    int row = base + rr;
    float m[8] = {0.f, 0.f, 0.f, 0.f, 0.f, 0.f, 0.f, 0.f};
    int beg = 0, end = 0;
    if (row < nrows) {
      beg = rowptr[row];
      end = rowptr[row + 1];
      if (beg < 0) beg = 0;
      if (end > E) end = E;
      for (int e0 = beg; e0 < end; e0 += 4) {
        int e = e0 + sub;
        if (e < end) {
          int s = srcList[e];
          s = s < 0 ? 0 : (s >= n_src ? n_src - 1 : s);
          uint4 u = *(const uint4*)(src_feat + (size_t)s * HDIM + ql * 8);
          m[0] += __uint_as_float(u.x << 16);
          m[1] += __uint_as_float(u.x & 0xffff0000u);
          m[2] += __uint_as_float(u.y << 16);
          m[3] += __uint_as_float(u.y & 0xffff0000u);
          m[4] += __uint_as_float(u.z << 16);
          m[5] += __uint_as_float(u.z & 0xffff0000u);
          m[6] += __uint_as_float(u.w << 16);
          m[7] += __uint_as_float(u.w & 0xffff0000u);
        }
      }
    }
    // cross-quarter butterfly (uniform across wave)
#pragma unroll
    for (int j = 0; j < 8; ++j) {
      m[j] += __shfl_xor(m[j], 16);
      m[j] += __shfl_xor(m[j], 32);
    }
    if (row < nrows && sub == 0) {
      float inv = 1.f / fmaxf((float)(end - beg), 1.f);
      uint4 st;
      st.x = pack_bf16(m[0] * inv, m[1] * inv);
      st.y = pack_bf16(m[2] * inv, m[3] * inv);
      st.z = pack_bf16(m[4] * inv, m[5] * inv);
      st.w = pack_bf16(m[6] * inv, m[7] * inv);
      char* rowp = (char*)&acts[rr][0];
      *(uint4*)(rowp + ql * 16) = st;  // mean cols ql*8..ql*8+7
      uint4 su = *(const uint4*)(self_feat + (size_t)row * HDIM + ql * 8);
      *(uint4*)(rowp + 256 + ql * 16) = su;  // self cols
    }
  }
  __syncthreads();

  // ---- GEMM: A-frag row=lane&15, k=(lane>>4)*8+j (contiguous b128) ----
  f32x4 acc0 = {0.f, 0.f, 0.f, 0.f};
  f32x4 acc1 = {0.f, 0.f, 0.f, 0.f};
  const char* abase = (const char*)&acts[0][0] + (lane & 15) * 528 +
                      (lane >> 4) * 16;
  const short8* b0p =
      (const short8*)(wfrag) + ((size_t)(w * 2) * 8 * 64 + lane);
  const short8* b1p =
      (const short8*)(wfrag) + ((size_t)(w * 2 + 1) * 8 * 64 + lane);
#pragma unroll
  for (int s = 0; s < 8; ++s) {
    short8 a = *(const short8*)(abase + s * 64);
    short8 b0 = b0p[s * 64];
    short8 b1 = b1p[s * 64];
    acc0 = __builtin_amdgcn_mfma_f32_16x16x32_bf16(a, b0, acc0, 0, 0, 0);
    acc1 = __builtin_amdgcn_mfma_f32_16x16x32_bf16(a, b1, acc1, 0, 0, 0);
  }

  // ---- epilogue: D row=(lane>>4)*4+j, col=lane&15 ----
  int col = lane & 15;
  int n0 = w * 32 + col, n1 = n0 + 16;
  float bv0 = bl[n0], bv1 = bl[n1];
  int mrow = (lane >> 4) * 4;
#pragma unroll
  for (int j = 0; j < 4; ++j) {
    int row = base + mrow + j;
    if (row < nrows) {
      stf(out, (size_t)row * HDIM + n0, fmaxf(acc0[j] + bv0, 0.f));
      stf(out, (size_t)row * HDIM + n1, fmaxf(acc1[j] + bv1, 0.f));
    }
  }
}

// ---- head: out = hc @ Wh^T + bh (OUT=2) ----
__global__ __launch_bounds__(256) void head_kernel(
    const bf16* __restrict__ hc, const float* __restrict__ Wh,
    const float* __restrict__ bh, float* __restrict__ out, int nrows) {
  __shared__ float sW[2 * HDIM];
  int tid = threadIdx.x;
  if (tid < 2 * HDIM) sW[tid] = Wh[tid];
  __syncthreads();
  int r = blockIdx.x * 64 + (tid >> 2);
  int sub = tid & 3;
  if (r >= nrows) return;
  const bf16* row = hc + (size_t)r * HDIM;
  float a0 = 0.f, a1 = 0.f;
#pragma unroll
  for (int i = 0; i < 16; ++i) {
    int k = sub * 32 + 2 * i;
    float2 v = ld2(row, k);
    a0 += v.x * sW[k] + v.y * sW[k + 1];
    a1 += v.x * sW[HDIM + k] + v.y * sW[HDIM + k + 1];
  }
  a0 += __shfl_xor(a0, 1);
  a0 += __shfl_xor(a0, 2);
  a1 += __shfl_xor(a1, 1);
  a1 += __shfl_xor(a1, 2);
  if (sub == 0) {
    out[(size_t)r * 2] = a0 + bh[0];
    out[(size_t)r * 2 + 1] = a1 + bh[1];
  }
}

// ---------------- host side ----------------
static const int NC = 400000, NN = 200000;

extern "C" void kernel_launch(void* const* d_in, const int* in_sizes, int n_in,
                              void* d_out, int out_size, void* d_ws,
                              size_t ws_size, hipStream_t stream) {
  const float* x_cell = (const float*)d_in[0];
  const float* x_net = (const float*)d_in[1];
  const void* e_drives = d_in[2];
  const void* e_fans = d_in[3];
  const float* Wc = (const float*)d_in[4];
  const float* bc = (const float*)d_in[5];
  const float* Wn = (const float*)d_in[6];
  const float* bn = (const float*)d_in[7];
  const float* Wl_dn = (const float*)d_in[8];
  const float* bl_dn = (const float*)d_in[9];
  const float* Wr_dn = (const float*)d_in[10];
  const float* Wl_nc = (const float*)d_in[11];
  const float* bl_nc = (const float*)d_in[12];
  const float* Wr_nc = (const float*)d_in[13];
  const float* Wh = (const float*)d_in[14];
  const float* bh = (const float*)d_in[15];
  float* out = (float*)d_out;

  const int Ed = in_sizes[2] / 2;
  const int Ef = in_sizes[3] / 2;

  char* p = (char*)d_ws;
  auto alloc = [&](size_t bytes) {
    char* r = p;
    p += (bytes + 255) & ~(size_t)255;
    return r;
  };
  int* flag = (int*)alloc(64);
  int* rowptrN = (int*)alloc((size_t)(NN + 1) * 4);
  int* rowptrC = (int*)alloc((size_t)(NC + 1) * 4);
  int* curN = (int*)alloc((size_t)NN * 4);
  int* curC = (int*)alloc((size_t)NC * 4);
  int* sums = (int*)alloc(4096 * 4);
  int* srcD = (int*)alloc((size_t)Ed * 4);   // cell ids, CSR by net
  int* srcF = (int*)alloc((size_t)Ef * 4);   // net ids, CSR by cell
  bf16* wfrag = (bf16*)alloc((size_t)6 * 32768 * sizeof(bf16));
  bf16* hc = (bf16*)alloc((size_t)NC * HDIM * sizeof(bf16));
  bf16* hnA = (bf16*)alloc((size_t)NN * HDIM * sizeof(bf16));
  bf16* hnB = (bf16*)alloc((size_t)NN * HDIM * sizeof(bf16));
  (void)ws_size;

  const int PN = (NN + 255) / 256, PC = (NC + 255) / 256;

  // ---- CSR build (once per call; reused by all 3 layers) ----
  zero_i<<<1, 64, 0, stream>>>(flag, 16);
  zero_i<<<512, 256, 0, stream>>>(curN, NN);
  zero_i<<<512, 256, 0, stream>>>(curC, NC);
  detect_kernel<<<16, 256, 0, stream>>>((const int*)e_drives, flag);
  count_kernel<<<2048, 256, 0, stream>>>(e_drives, flag, Ed, curN, NN);
  count_kernel<<<2048, 256, 0, stream>>>(e_fans, flag, Ef, curC, NC);
  scan1_kernel<<<PN, 256, 0, stream>>>(curN, rowptrN, sums, NN);
  scan2_kernel<<<1, 256, 0, stream>>>(sums, PN);
  scan3_kernel<<<512, 256, 0, stream>>>(rowptrN, curN, sums, NN);
  scan1_kernel<<<PC, 256, 0, stream>>>(curC, rowptrC, sums, NC);
  scan2_kernel<<<1, 256, 0, stream>>>(sums, PC);
  scan3_kernel<<<512, 256, 0, stream>>>(rowptrC, curC, sums, NC);
  fill_kernel<<<2048, 256, 0, stream>>>(e_drives, flag, Ed, curN, srcD, NC, NN);
  fill_kernel<<<2048, 256, 0, stream>>>(e_fans, flag, Ef, curC, srcF, NN, NC);

  // ---- W fragment pre-convert + input projections ----
  wfrag_kernel<<<192, 256, 0, stream>>>(Wl_dn, Wr_dn, Wl_nc, Wr_nc, wfrag);
  proj_kernel<16><<<NC / 8, 256, 0, stream>>>(x_cell, Wc, bc, hc, NC);
  proj_kernel<8><<<NN / 8, 256, 0, stream>>>(x_net, Wn, bn, hnA, NN);

  bf16* hn_cur = hnA;
  bf16* hn_nxt = hnB;

  for (int l = 0; l < 3; ++l) {
    // nets: hn_nxt = relu(sage(hc -> nets, self=hn_cur))
    sage_mfma_kernel<<<(NN + 15) / 16, 256, 0, stream>>>(
        hc, hn_cur, rowptrN, srcD, NC, Ed, wfrag + (size_t)(l * 2) * 32768,
        bl_dn + (size_t)l * HDIM, hn_nxt, NN);
    // cells: hc = relu(sage(hn_cur -> cells, self=hc)) in place
    sage_mfma_kernel<<<(NC + 15) / 16, 256, 0, stream>>>(
        hn_cur, hc, rowptrC, srcF, NN, Ef, wfrag + (size_t)(l * 2 + 1) * 32768,
        bl_nc + (size_t)l * HDIM, hc, NC);
    bf16* t = hn_cur;
    hn_cur = hn_nxt;
    hn_nxt = t;
  }

  head_kernel<<<(NC + 63) / 64, 256, 0, stream>>>(hc, Wh, bh, out, NC);
}